// Round 1
// baseline (382.578 us; speedup 1.0000x reference)
//
#include <hip/hip_runtime.h>
#include <hip/hip_bf16.h>
#include <cstdint>
#include <cstddef>

// Problem constants
#define BB 4
#define LL 4096
#define HH 16
#define M1 16384      // B*L
#define E3 3072
#define EE 1024
#define ANGC 3.8349519697141029e-4f   // (pi/2)/4096
#define EPSC 1e-4f

typedef __attribute__((ext_vector_type(8))) short bf16x8;
typedef __attribute__((ext_vector_type(4))) float f32x4;
typedef __attribute__((ext_vector_type(8))) unsigned short us8;

static __device__ __forceinline__ float bf2f(unsigned short u) {
  union { unsigned int i; float f; } a; a.i = ((unsigned int)u) << 16; return a.f;
}
static __device__ __forceinline__ unsigned short f2bf(float x) {
  union { float f; unsigned int i; } a; a.f = x;
  unsigned int r = a.i + 0x7FFFu + ((a.i >> 16) & 1u);  // RNE
  return (unsigned short)(r >> 16);
}
static __device__ __forceinline__ void gload16(const void* g, void* l) {
  __builtin_amdgcn_global_load_lds((const __attribute__((address_space(1))) void*)g,
                                   (__attribute__((address_space(3))) void*)l, 16, 0, 0);
}

// ---------------- elementwise f32 -> bf16 (x) ----------------
__global__ __launch_bounds__(256) void k_cvt_bf16(const float* __restrict__ src,
                                                  unsigned short* __restrict__ dst, int n8) {
  int i = blockIdx.x * 256 + threadIdx.x;
  if (i >= n8) return;
  const float4* s = (const float4*)src + (size_t)i * 2;
  float4 a = s[0], b = s[1];
  us8 o;
  o[0]=f2bf(a.x); o[1]=f2bf(a.y); o[2]=f2bf(a.z); o[3]=f2bf(a.w);
  o[4]=f2bf(b.x); o[5]=f2bf(b.y); o[6]=f2bf(b.z); o[7]=f2bf(b.w);
  *(us8*)(dst + (size_t)i * 8) = o;
}

// ---------------- tiled transpose f32 [R][C] -> bf16 [C][R] ----------------
__global__ __launch_bounds__(256) void k_transpose_bf16(const float* __restrict__ src,
                                                        unsigned short* __restrict__ dst,
                                                        int R, int C) {
  __shared__ float tile[32][33];
  int c0 = blockIdx.x * 32, r0 = blockIdx.y * 32;
  int tx = threadIdx.x & 31, ty = threadIdx.x >> 5;
#pragma unroll
  for (int k = 0; k < 4; ++k)
    tile[ty + 8*k][tx] = src[(size_t)(r0 + ty + 8*k) * C + c0 + tx];
  __syncthreads();
#pragma unroll
  for (int k = 0; k < 4; ++k)
    dst[(size_t)(c0 + ty + 8*k) * R + r0 + tx] = f2bf(tile[tx][ty + 8*k]);
}

// ---------------- bf16 MFMA GEMM: C[M,N] = A[M,K] @ Bt[N,K]^T + bias ----------------
// MODE 0: bf16 out, relu on cols<2048 (qkv). MODE 1: f32 out (final).
// 128x128 tile, BK=32, 4 waves (2x2), each wave 64x64 via 4x4 16x16x32 MFMA.
// LDS layout [kq(4)][row(128)][8 bf16] so frag ds_read_b128 spreads banks.
template<int MODE>
__global__ __launch_bounds__(256, 2) void k_gemm(const unsigned short* __restrict__ A,
                                                 const unsigned short* __restrict__ Bt,
                                                 const float* __restrict__ bias,
                                                 void* __restrict__ Cout,
                                                 int N, int K) {
  __shared__ __align__(16) unsigned short lds[8192];   // A: 0..4095, B: 4096..8191
  unsigned short* lds_a = lds;
  unsigned short* lds_b = lds + 4096;
  const int tid = threadIdx.x;
  const int wid = tid >> 6, lane = tid & 63;
  const int lr = lane & 15, lg = lane >> 4;
  const int wr = wid >> 1, wc = wid & 1;
  const int bm = blockIdx.y * 128, bn = blockIdx.x * 128;

  f32x4 acc[4][4] = {};

  const int r0c = tid & 127, q0c = tid >> 7;          // chunk tid
  const int ch2 = tid + 256;
  const int r1c = ch2 & 127, q1c = ch2 >> 7;          // chunk tid+256

  for (int kt = 0; kt < K; kt += 32) {
    __syncthreads();
    gload16(A  + (size_t)(bm + r0c) * K + kt + q0c*8, lds_a + tid*8);
    gload16(A  + (size_t)(bm + r1c) * K + kt + q1c*8, lds_a + ch2*8);
    gload16(Bt + (size_t)(bn + r0c) * K + kt + q0c*8, lds_b + tid*8);
    gload16(Bt + (size_t)(bn + r1c) * K + kt + q1c*8, lds_b + ch2*8);
    __syncthreads();
    bf16x8 af[4], bf[4];
#pragma unroll
    for (int m = 0; m < 4; ++m)
      af[m] = *(const bf16x8*)(lds_a + (lg*128 + wr*64 + m*16 + lr) * 8);
#pragma unroll
    for (int n = 0; n < 4; ++n)
      bf[n] = *(const bf16x8*)(lds_b + (lg*128 + wc*64 + n*16 + lr) * 8);
#pragma unroll
    for (int m = 0; m < 4; ++m)
#pragma unroll
      for (int n = 0; n < 4; ++n)
        acc[m][n] = __builtin_amdgcn_mfma_f32_16x16x32_bf16(af[m], bf[n], acc[m][n], 0, 0, 0);
  }

  // Epilogue: per-wave LDS transpose strip [16][64] f32 for coalesced stores
  __syncthreads();
  float* strip = (float*)lds + wid * 1024;  // 4KB per wave
  float bias_v[4]; bool relu_v[4];
#pragma unroll
  for (int n = 0; n < 4; ++n) {
    int col = bn + wc*64 + n*16 + lr;
    bias_v[n] = bias[col];
    relu_v[n] = (MODE == 0) && (col < 2048);
  }
#pragma unroll
  for (int m = 0; m < 4; ++m) {
#pragma unroll
    for (int n = 0; n < 4; ++n)
#pragma unroll
      for (int j = 0; j < 4; ++j) {
        float v = acc[m][n][j] + bias_v[n];
        if (relu_v[n]) v = fmaxf(v, 0.0f);
        strip[(lg*4 + j)*64 + n*16 + lr] = v;
      }
    __syncthreads();
#pragma unroll
    for (int p = 0; p < 2; ++p) {
      int ch = p*64 + lane;
      int row = ch >> 3, cg = ch & 7;
      float4 v0 = *(const float4*)(strip + row*64 + cg*8);
      float4 v1 = *(const float4*)(strip + row*64 + cg*8 + 4);
      size_t base = (size_t)(bm + wr*64 + m*16 + row) * N + bn + wc*64 + cg*8;
      if (MODE == 0) {
        us8 o;
        o[0]=f2bf(v0.x); o[1]=f2bf(v0.y); o[2]=f2bf(v0.z); o[3]=f2bf(v0.w);
        o[4]=f2bf(v1.x); o[5]=f2bf(v1.y); o[6]=f2bf(v1.z); o[7]=f2bf(v1.w);
        *(us8*)((unsigned short*)Cout + base) = o;
      } else {
        float* op = (float*)Cout + base;
        *(float4*)op = v0;
        *(float4*)(op + 4) = v1;
      }
    }
    __syncthreads();
  }
}

// ---------------- stage2: per-head KVc^T/KVs^T accumulation + k-sums ----------------
// grid (16 l-chunks, 64 heads). Block covers 256 l in 4 sub-chunks of 64.
// LDS: kcT/ksT/vT [64 row][64 l] bf16, XOR-swizzled 16B chunks by (row&7).
// MFMA: D[e][d] = sum_l vT[e][l] * k{c,s}T^T -> kvb[head][mt][e][d] (f32 atomics).
__global__ __launch_bounds__(256) void k_stage2(const unsigned short* __restrict__ qkv,
                                                float* __restrict__ kvb,
                                                float* __restrict__ ksumb) {
  __shared__ __align__(16) unsigned short kcT[4096];
  __shared__ __align__(16) unsigned short ksT[4096];
  __shared__ __align__(16) unsigned short vT [4096];
  const int tid = threadIdx.x;
  const int head = blockIdx.y;
  const int b = head >> 4, h = head & 15;
  const int lane = tid & 63, wid = tid >> 6;
  const int lr = lane & 15, lg = lane >> 4;
  const int mt = wid >> 1, eh = wid & 1;
  const int lp = tid & 31;        // l-pair: l = 2lp, 2lp+1
  const int piece = tid >> 5;     // d-range piece*8..+7

  f32x4 acc[2][4] = {};
  float ksacc = 0.0f;
  const int mtk = tid >> 6, dk = tid & 63;   // ksum role (tid<128)
  const size_t qbase = (size_t)b * LL * E3;

  for (int sc = 0; sc < 4; ++sc) {
    const int lbase = blockIdx.x * 256 + sc * 64;
    __syncthreads();
    {
      const int l0 = 2 * lp;
      const int p0 = lbase + l0;
      float s0, c0, s1, c1;
      __sincosf((float)p0 * ANGC, &s0, &c0);
      __sincosf((float)(p0 + 1) * ANGC, &s1, &c1);
      const unsigned short* kp = qkv + qbase + (size_t)p0 * E3 + 1024 + h*64 + piece*8;
      us8 kr0 = *(const us8*)kp;
      us8 kr1 = *(const us8*)(kp + E3);
      us8 vr0 = *(const us8*)(kp + 1024);
      us8 vr1 = *(const us8*)(kp + 1024 + E3);
#pragma unroll
      for (int i = 0; i < 8; ++i) {
        int d = piece*8 + i;
        float ka = bf2f(kr0[i]), kb = bf2f(kr1[i]);
        unsigned int kcp = (unsigned int)f2bf(c0*ka) | ((unsigned int)f2bf(c1*kb) << 16);
        unsigned int ksp = (unsigned int)f2bf(s0*ka) | ((unsigned int)f2bf(s1*kb) << 16);
        unsigned int vp  = (unsigned int)vr0[i] | ((unsigned int)vr1[i] << 16);
        int off = d*128 + ((((l0 >> 3) ^ (d & 7))) << 4) + (l0 & 7) * 2;
        *(unsigned int*)((char*)kcT + off) = kcp;
        *(unsigned int*)((char*)ksT + off) = ksp;
        *(unsigned int*)((char*)vT  + off) = vp;
      }
    }
    __syncthreads();
    if (tid < 128) {   // k-sums: row-sum over l of kcT/ksT row dk
      const unsigned short* basep = mtk ? ksT : kcT;
      float sum = 0.0f;
#pragma unroll
      for (int cch = 0; cch < 8; ++cch) {
        us8 r = *(const us8*)((const char*)basep + dk*128 + ((cch ^ (dk & 7)) << 4));
#pragma unroll
        for (int i = 0; i < 8; ++i) sum += bf2f(r[i]);
      }
      ksacc += sum;
    }
    {
      const unsigned short* kT = mt ? ksT : kcT;
      bf16x8 af[2][2], bf[2][4];
#pragma unroll
      for (int kk = 0; kk < 2; ++kk) {
#pragma unroll
        for (int m = 0; m < 2; ++m) {
          int e = eh*32 + m*16 + lr;
          af[kk][m] = *(const bf16x8*)((const char*)vT + e*128 + ((((kk*4)+lg) ^ (e & 7)) << 4));
        }
#pragma unroll
        for (int n = 0; n < 4; ++n) {
          int d = n*16 + lr;
          bf[kk][n] = *(const bf16x8*)((const char*)kT + d*128 + ((((kk*4)+lg) ^ (d & 7)) << 4));
        }
      }
#pragma unroll
      for (int kk = 0; kk < 2; ++kk)
#pragma unroll
        for (int m = 0; m < 2; ++m)
#pragma unroll
          for (int n = 0; n < 4; ++n)
            acc[m][n] = __builtin_amdgcn_mfma_f32_16x16x32_bf16(af[kk][m], bf[kk][n], acc[m][n], 0, 0, 0);
    }
  }
  float* dst = kvb + (size_t)head * 8192 + mt * 4096;
#pragma unroll
  for (int m = 0; m < 2; ++m)
#pragma unroll
    for (int n = 0; n < 4; ++n)
#pragma unroll
      for (int j = 0; j < 4; ++j) {
        int e = eh*32 + m*16 + lg*4 + j;
        int d = n*16 + lr;
        atomicAdd(&dst[e*64 + d], acc[m][n][j]);
      }
  if (tid < 128) atomicAdd(&ksumb[head*128 + mtk*64 + dk], ksacc);
}

// ---------------- stage3: context + norm + divide -> att bf16 [B*L][E] ----------------
// grid (32 l-chunks of 128, 64 heads). B matrix in LDS: [144 cols][64 d] bf16:
// cols 0..63 KVc^T rows(e), 64..127 KVs^T, 128 ksc, 129 kss, 130..143 zero.
__global__ __launch_bounds__(256) void k_stage3(const unsigned short* __restrict__ qkv,
                                                const float* __restrict__ kvb,
                                                const float* __restrict__ ksumb,
                                                unsigned short* __restrict__ att) {
  __shared__ __align__(16) unsigned short Bl[144 * 64];   // 18KB; reused as strips
  const int tid = threadIdx.x;
  const int head = blockIdx.y;
  const int b = head >> 4, h = head & 15;
  const int l0 = blockIdx.x * 128;
  const int lane = tid & 63, w = tid >> 6;
  const int lr = lane & 15, lg = lane >> 4;

  { // load B into LDS (bf16, XOR-swizzled chunks by (col&7))
    int c = tid >> 1, half = tid & 1;
    const float* src = kvb + (size_t)head * 8192 + (c >> 6) * 4096 + (c & 63) * 64 + half * 32;
    float fv[32];
#pragma unroll
    for (int q = 0; q < 8; ++q) *(float4*)(fv + q*4) = *(const float4*)(src + q*4);
#pragma unroll
    for (int q2 = 0; q2 < 4; ++q2) {
      us8 o;
#pragma unroll
      for (int i = 0; i < 8; ++i) o[i] = f2bf(fv[q2*8 + i]);
      int chunk = half*4 + q2;
      *(us8*)((char*)Bl + c*128 + ((chunk ^ (c & 7)) << 4)) = o;
    }
    if (tid < 16) {
      int cc = 128 + (tid >> 3), q = tid & 7;
      const float* s2 = ksumb + head*128 + (tid >> 3)*64 + q*8;
      us8 o;
#pragma unroll
      for (int i = 0; i < 8; ++i) o[i] = f2bf(s2[i]);
      *(us8*)((char*)Bl + cc*128 + ((q ^ (cc & 7)) << 4)) = o;
    } else if (tid < 128) {
      int idx = tid - 16;
      int cc = 130 + (idx >> 3), q = idx & 7;
      us8 o = {0,0,0,0,0,0,0,0};
      *(us8*)((char*)Bl + cc*128 + ((q ^ (cc & 7)) << 4)) = o;
    }
  }
  __syncthreads();

  f32x4 acc[2][9] = {};
  bf16x8 af[2][2];
  const size_t qrow0 = (size_t)(b * LL + l0 + w * 32);
#pragma unroll
  for (int kk = 0; kk < 2; ++kk)
#pragma unroll
    for (int m = 0; m < 2; ++m)
      af[m][kk] = *(const bf16x8*)(qkv + (qrow0 + m*16 + lr) * E3 + h*64 + kk*32 + lg*8);
#pragma unroll
  for (int kk = 0; kk < 2; ++kk)
#pragma unroll
    for (int n = 0; n < 9; ++n) {
      int cc = n*16 + lr;
      bf16x8 bb = *(const bf16x8*)((const char*)Bl + cc*128 + ((((kk*4)+lg) ^ (cc & 7)) << 4));
#pragma unroll
      for (int m = 0; m < 2; ++m)
        acc[m][n] = __builtin_amdgcn_mfma_f32_16x16x32_bf16(af[m][kk], bb, acc[m][n], 0, 0, 0);
    }

  __syncthreads();   // Bl reads done; reuse as per-wave strips
  unsigned short* strip = (unsigned short*)Bl + w * 2048;   // [32][64] bf16
#pragma unroll
  for (int m = 0; m < 2; ++m)
#pragma unroll
    for (int j = 0; j < 4; ++j) {
      int rloc = m*16 + lg*4 + j;
      int pos = l0 + w*32 + rloc;
      float s_, c_;
      __sincosf((float)pos * ANGC, &s_, &c_);
      float nc = __shfl(acc[m][8][j], lane & 48, 64);          // col 128 (lr=0)
      float ns = __shfl(acc[m][8][j], (lane & 48) | 1, 64);    // col 129 (lr=1)
      float rn = 1.0f / (c_ * nc + s_ * ns + EPSC);
#pragma unroll
      for (int n = 0; n < 4; ++n) {
        float ctx = (c_ * acc[m][n][j] + s_ * acc[m][n+4][j]) * rn;
        strip[rloc*64 + n*16 + lr] = f2bf(ctx);
      }
    }
  __syncthreads();
#pragma unroll
  for (int p = 0; p < 4; ++p) {
    int ch = p*64 + lane;
    int row = ch >> 3, piece = ch & 7;
    us8 o = *(const us8*)(strip + row*64 + piece*8);
    *(us8*)(att + (size_t)(b*LL + l0 + w*32 + row) * EE + h*64 + piece*8) = o;
  }
}

// ---------------- launcher ----------------
extern "C" void kernel_launch(void* const* d_in, const int* in_sizes, int n_in,
                              void* d_out, int out_size, void* d_ws, size_t ws_size,
                              hipStream_t stream) {
  const float* x     = (const float*)d_in[0];
  const float* W_qkv = (const float*)d_in[1];
  const float* b_qkv = (const float*)d_in[2];
  const float* W_out = (const float*)d_in[3];
  const float* b_out = (const float*)d_in[4];

  char* w = (char*)d_ws;
  unsigned short* xb  = (unsigned short*)(w);                 // 33,554,432 B
  unsigned short* qkv = (unsigned short*)(w + 33554432);      // 100,663,296 B
  unsigned short* WqT = (unsigned short*)(w + 134217728);     // 6,291,456 B
  unsigned short* WoT = (unsigned short*)(w + 140509184);     // 2,097,152 B
  float* kvb   = (float*)(w + 142606336);                     // 2,097,152 B
  float* ksum  = (float*)(w + 144703488);                     // 32,768 B  (total 144,736,256)
  unsigned short* att = xb;   // reuse: x dead after GEMM1

  hipMemsetAsync(kvb, 0, 2097152 + 32768, stream);
  k_cvt_bf16<<<8192, 256, 0, stream>>>(x, xb, 2097152);
  k_transpose_bf16<<<dim3(96, 32), 256, 0, stream>>>(W_qkv, WqT, 1024, 3072);
  k_transpose_bf16<<<dim3(32, 32), 256, 0, stream>>>(W_out, WoT, 1024, 1024);
  k_gemm<0><<<dim3(24, 128), 256, 0, stream>>>(xb, WqT, b_qkv, (void*)qkv, 3072, 1024);
  k_stage2<<<dim3(16, 64), 256, 0, stream>>>(qkv, kvb, ksum);
  k_stage3<<<dim3(32, 64), 256, 0, stream>>>(qkv, kvb, ksum, att);
  k_gemm<1><<<dim3(8, 128), 256, 0, stream>>>(att, WoT, b_out, d_out, 1024, 1024);
}

// Round 2
// 268.660 us; speedup vs baseline: 1.4240x; 1.4240x over previous
//
#include <hip/hip_runtime.h>
#include <hip/hip_bf16.h>
#include <cstdint>
#include <cstddef>

// Problem constants
#define BB 4
#define LL 4096
#define HH 16
#define M1 16384      // B*L
#define E3 3072
#define EE 1024
#define ANGC 3.8349519697141029e-4f   // (pi/2)/4096
#define EPSC 1e-4f

typedef __attribute__((ext_vector_type(8))) short bf16x8;
typedef __attribute__((ext_vector_type(4))) float f32x4;
typedef __attribute__((ext_vector_type(8))) unsigned short us8;

static __device__ __forceinline__ float bf2f(unsigned short u) {
  union { unsigned int i; float f; } a; a.i = ((unsigned int)u) << 16; return a.f;
}
static __device__ __forceinline__ unsigned short f2bf(float x) {
  union { float f; unsigned int i; } a; a.f = x;
  unsigned int r = a.i + 0x7FFFu + ((a.i >> 16) & 1u);  // RNE
  return (unsigned short)(r >> 16);
}
static __device__ __forceinline__ void gload16(const void* g, void* l) {
  __builtin_amdgcn_global_load_lds((const __attribute__((address_space(1))) void*)g,
                                   (__attribute__((address_space(3))) void*)l, 16, 0, 0);
}

// ---------------- elementwise f32 -> bf16 (x) ----------------
__global__ __launch_bounds__(256) void k_cvt_bf16(const float* __restrict__ src,
                                                  unsigned short* __restrict__ dst, int n8) {
  int i = blockIdx.x * 256 + threadIdx.x;
  if (i >= n8) return;
  const float4* s = (const float4*)src + (size_t)i * 2;
  float4 a = s[0], b = s[1];
  us8 o;
  o[0]=f2bf(a.x); o[1]=f2bf(a.y); o[2]=f2bf(a.z); o[3]=f2bf(a.w);
  o[4]=f2bf(b.x); o[5]=f2bf(b.y); o[6]=f2bf(b.z); o[7]=f2bf(b.w);
  *(us8*)(dst + (size_t)i * 8) = o;
}

// ---------------- tiled transpose f32 [R][C] -> bf16 [C][R] ----------------
__global__ __launch_bounds__(256) void k_transpose_bf16(const float* __restrict__ src,
                                                        unsigned short* __restrict__ dst,
                                                        int R, int C) {
  __shared__ float tile[32][33];
  int c0 = blockIdx.x * 32, r0 = blockIdx.y * 32;
  int tx = threadIdx.x & 31, ty = threadIdx.x >> 5;
#pragma unroll
  for (int k = 0; k < 4; ++k)
    tile[ty + 8*k][tx] = src[(size_t)(r0 + ty + 8*k) * C + c0 + tx];
  __syncthreads();
#pragma unroll
  for (int k = 0; k < 4; ++k)
    dst[(size_t)(c0 + ty + 8*k) * R + r0 + tx] = f2bf(tile[tx][ty + 8*k]);
}

// ---------------- bf16 MFMA GEMM: C[M,N] = A[M,K] @ Bt[N,K]^T + bias ----------------
// MODE 0: bf16 out, relu on cols<2048 (qkv). MODE 1: f32 out (final).
// 128x128 tile, BK=32, 4 waves (2x2), each wave 64x64 via 4x4 16x16x32 MFMA.
// Staging: 4-lane groups cover one row's 64B (16 cache lines / wave-instr).
// LDS row-major [128 rows][4 chunks][8 bf16], chunk XOR-swizzle cs = c ^ ((row>>1)&3),
// applied on BOTH sides: inverse-swizzled global source + swizzled ds_read (rule #21).
// Double-buffered: stage tile t+1 before computing tile t; ONE barrier per K-step.
template<int MODE>
__global__ __launch_bounds__(256, 2) void k_gemm(const unsigned short* __restrict__ A,
                                                 const unsigned short* __restrict__ Bt,
                                                 const float* __restrict__ bias,
                                                 void* __restrict__ Cout,
                                                 int N, int K) {
  __shared__ __align__(16) unsigned short lds[2][8192];   // per buf: A 0..4095, B 4096..8191
  const int tid = threadIdx.x;
  const int wid = tid >> 6, lane = tid & 63;
  const int lr = lane & 15, lg = lane >> 4;
  const int wr = wid >> 1, wc = wid & 1;

  // T1 bijective XCD swizzle (nwg % 8 == 0 for both GEMMs)
  const int nx = gridDim.x;
  const int nwg = nx * gridDim.y;
  const int bid = blockIdx.y * nx + blockIdx.x;
  const int swz = (bid & 7) * (nwg >> 3) + (bid >> 3);
  const int bm = (swz / nx) * 128, bn = (swz % nx) * 128;

  f32x4 acc[4][4] = {};

  // staging roles: thread t covers (row = j*64 + (t>>2), stored-chunk = t&3), j = 0,1
  const int srow = tid >> 2, scs = tid & 3;
  const int ra0 = srow,       ca0 = scs ^ ((ra0 >> 1) & 3);
  const int ra1 = 64 + srow,  ca1 = scs ^ ((ra1 >> 1) & 3);

#define STAGE(bufi, ktv)                                                          \
  { unsigned short* la = lds[bufi];                                               \
    unsigned short* lb = lds[bufi] + 4096;                                        \
    gload16(A  + (size_t)(bm + ra0) * K + (ktv) + ca0*8, la + tid*8);             \
    gload16(A  + (size_t)(bm + ra1) * K + (ktv) + ca1*8, la + (256+tid)*8);       \
    gload16(Bt + (size_t)(bn + ra0) * K + (ktv) + ca0*8, lb + tid*8);             \
    gload16(Bt + (size_t)(bn + ra1) * K + (ktv) + ca1*8, lb + (256+tid)*8); }

  STAGE(0, 0);
  __syncthreads();
  int buf = 0;
  for (int kt = 0; kt < K; kt += 32) {
    if (kt + 32 < K) STAGE(buf ^ 1, kt + 32);
    const unsigned short* la = lds[buf];
    const unsigned short* lb = lds[buf] + 4096;
    bf16x8 af[4], bf[4];
#pragma unroll
    for (int m = 0; m < 4; ++m) {
      int row = wr*64 + m*16 + lr;
      af[m] = *(const bf16x8*)((const char*)la + row*64 + ((lg ^ ((row >> 1) & 3)) << 4));
    }
#pragma unroll
    for (int n = 0; n < 4; ++n) {
      int row = wc*64 + n*16 + lr;
      bf[n] = *(const bf16x8*)((const char*)lb + row*64 + ((lg ^ ((row >> 1) & 3)) << 4));
    }
#pragma unroll
    for (int m = 0; m < 4; ++m)
#pragma unroll
      for (int n = 0; n < 4; ++n)
        acc[m][n] = __builtin_amdgcn_mfma_f32_16x16x32_bf16(af[m], bf[n], acc[m][n], 0, 0, 0);
    __syncthreads();   // drains vmcnt (next-tile stage) + ensures all frag reads of buf done
    buf ^= 1;
  }
#undef STAGE

  // Epilogue: per-wave LDS transpose strip [16][64] f32 for coalesced stores
  float* strip = (float*)&lds[0][0] + wid * 1024;  // 4KB per wave (16KB of 32KB)
  float bias_v[4]; bool relu_v[4];
#pragma unroll
  for (int n = 0; n < 4; ++n) {
    int col = bn + wc*64 + n*16 + lr;
    bias_v[n] = bias[col];
    relu_v[n] = (MODE == 0) && (col < 2048);
  }
#pragma unroll
  for (int m = 0; m < 4; ++m) {
#pragma unroll
    for (int n = 0; n < 4; ++n)
#pragma unroll
      for (int j = 0; j < 4; ++j) {
        float v = acc[m][n][j] + bias_v[n];
        if (relu_v[n]) v = fmaxf(v, 0.0f);
        strip[(lg*4 + j)*64 + n*16 + lr] = v;
      }
    __syncthreads();
#pragma unroll
    for (int p = 0; p < 2; ++p) {
      int ch = p*64 + lane;
      int row = ch >> 3, cg = ch & 7;
      float4 v0 = *(const float4*)(strip + row*64 + cg*8);
      float4 v1 = *(const float4*)(strip + row*64 + cg*8 + 4);
      size_t base = (size_t)(bm + wr*64 + m*16 + row) * N + bn + wc*64 + cg*8;
      if (MODE == 0) {
        us8 o;
        o[0]=f2bf(v0.x); o[1]=f2bf(v0.y); o[2]=f2bf(v0.z); o[3]=f2bf(v0.w);
        o[4]=f2bf(v1.x); o[5]=f2bf(v1.y); o[6]=f2bf(v1.z); o[7]=f2bf(v1.w);
        *(us8*)((unsigned short*)Cout + base) = o;
      } else {
        float* op = (float*)Cout + base;
        *(float4*)op = v0;
        *(float4*)(op + 4) = v1;
      }
    }
    __syncthreads();
  }
}

// ---------------- stage2: per-head KVc^T/KVs^T accumulation + k-sums ----------------
// grid (16 l-chunks, 64 heads). Block covers 256 l in 4 sub-chunks of 64.
// LDS: kcT/ksT/vT [64 row][64 l] bf16, XOR-swizzled 16B chunks by (row&7).
// MFMA: D[e][d] = sum_l vT[e][l] * k{c,s}T^T -> kvb[head][mt][e][d] (f32 atomics).
__global__ __launch_bounds__(256) void k_stage2(const unsigned short* __restrict__ qkv,
                                                float* __restrict__ kvb,
                                                float* __restrict__ ksumb) {
  __shared__ __align__(16) unsigned short kcT[4096];
  __shared__ __align__(16) unsigned short ksT[4096];
  __shared__ __align__(16) unsigned short vT [4096];
  const int tid = threadIdx.x;
  const int head = blockIdx.y;
  const int b = head >> 4, h = head & 15;
  const int lane = tid & 63, wid = tid >> 6;
  const int lr = lane & 15, lg = lane >> 4;
  const int mt = wid >> 1, eh = wid & 1;
  const int lp = tid & 31;        // l-pair: l = 2lp, 2lp+1
  const int piece = tid >> 5;     // d-range piece*8..+7

  f32x4 acc[2][4] = {};
  float ksacc = 0.0f;
  const int mtk = tid >> 6, dk = tid & 63;   // ksum role (tid<128)
  const size_t qbase = (size_t)b * LL * E3;

  for (int sc = 0; sc < 4; ++sc) {
    const int lbase = blockIdx.x * 256 + sc * 64;
    __syncthreads();
    {
      const int l0 = 2 * lp;
      const int p0 = lbase + l0;
      float s0, c0, s1, c1;
      __sincosf((float)p0 * ANGC, &s0, &c0);
      __sincosf((float)(p0 + 1) * ANGC, &s1, &c1);
      const unsigned short* kp = qkv + qbase + (size_t)p0 * E3 + 1024 + h*64 + piece*8;
      us8 kr0 = *(const us8*)kp;
      us8 kr1 = *(const us8*)(kp + E3);
      us8 vr0 = *(const us8*)(kp + 1024);
      us8 vr1 = *(const us8*)(kp + 1024 + E3);
#pragma unroll
      for (int i = 0; i < 8; ++i) {
        int d = piece*8 + i;
        float ka = bf2f(kr0[i]), kb = bf2f(kr1[i]);
        unsigned int kcp = (unsigned int)f2bf(c0*ka) | ((unsigned int)f2bf(c1*kb) << 16);
        unsigned int ksp = (unsigned int)f2bf(s0*ka) | ((unsigned int)f2bf(s1*kb) << 16);
        unsigned int vp  = (unsigned int)vr0[i] | ((unsigned int)vr1[i] << 16);
        int off = d*128 + ((((l0 >> 3) ^ (d & 7))) << 4) + (l0 & 7) * 2;
        *(unsigned int*)((char*)kcT + off) = kcp;
        *(unsigned int*)((char*)ksT + off) = ksp;
        *(unsigned int*)((char*)vT  + off) = vp;
      }
    }
    __syncthreads();
    if (tid < 128) {   // k-sums: row-sum over l of kcT/ksT row dk
      const unsigned short* basep = mtk ? ksT : kcT;
      float sum = 0.0f;
#pragma unroll
      for (int cch = 0; cch < 8; ++cch) {
        us8 r = *(const us8*)((const char*)basep + dk*128 + ((cch ^ (dk & 7)) << 4));
#pragma unroll
        for (int i = 0; i < 8; ++i) sum += bf2f(r[i]);
      }
      ksacc += sum;
    }
    {
      const unsigned short* kT = mt ? ksT : kcT;
      bf16x8 af[2][2], bf[2][4];
#pragma unroll
      for (int kk = 0; kk < 2; ++kk) {
#pragma unroll
        for (int m = 0; m < 2; ++m) {
          int e = eh*32 + m*16 + lr;
          af[kk][m] = *(const bf16x8*)((const char*)vT + e*128 + ((((kk*4)+lg) ^ (e & 7)) << 4));
        }
#pragma unroll
        for (int n = 0; n < 4; ++n) {
          int d = n*16 + lr;
          bf[kk][n] = *(const bf16x8*)((const char*)kT + d*128 + ((((kk*4)+lg) ^ (d & 7)) << 4));
        }
      }
#pragma unroll
      for (int kk = 0; kk < 2; ++kk)
#pragma unroll
        for (int m = 0; m < 2; ++m)
#pragma unroll
          for (int n = 0; n < 4; ++n)
            acc[m][n] = __builtin_amdgcn_mfma_f32_16x16x32_bf16(af[kk][m], bf[kk][n], acc[m][n], 0, 0, 0);
    }
  }
  float* dst = kvb + (size_t)head * 8192 + mt * 4096;
#pragma unroll
  for (int m = 0; m < 2; ++m)
#pragma unroll
    for (int n = 0; n < 4; ++n)
#pragma unroll
      for (int j = 0; j < 4; ++j) {
        int e = eh*32 + m*16 + lg*4 + j;
        int d = n*16 + lr;
        atomicAdd(&dst[e*64 + d], acc[m][n][j]);
      }
  if (tid < 128) atomicAdd(&ksumb[head*128 + mtk*64 + dk], ksacc);
}

// ---------------- stage3: context + norm + divide -> att bf16 [B*L][E] ----------------
// grid (32 l-chunks of 128, 64 heads). B matrix in LDS: [144 cols][64 d] bf16:
// cols 0..63 KVc^T rows(e), 64..127 KVs^T, 128 ksc, 129 kss, 130..143 zero.
__global__ __launch_bounds__(256) void k_stage3(const unsigned short* __restrict__ qkv,
                                                const float* __restrict__ kvb,
                                                const float* __restrict__ ksumb,
                                                unsigned short* __restrict__ att) {
  __shared__ __align__(16) unsigned short Bl[144 * 64];   // 18KB; reused as strips
  const int tid = threadIdx.x;
  const int head = blockIdx.y;
  const int b = head >> 4, h = head & 15;
  const int l0 = blockIdx.x * 128;
  const int lane = tid & 63, w = tid >> 6;
  const int lr = lane & 15, lg = lane >> 4;

  { // load B into LDS (bf16, XOR-swizzled chunks by (col&7))
    int c = tid >> 1, half = tid & 1;
    const float* src = kvb + (size_t)head * 8192 + (c >> 6) * 4096 + (c & 63) * 64 + half * 32;
    float fv[32];
#pragma unroll
    for (int q = 0; q < 8; ++q) *(float4*)(fv + q*4) = *(const float4*)(src + q*4);
#pragma unroll
    for (int q2 = 0; q2 < 4; ++q2) {
      us8 o;
#pragma unroll
      for (int i = 0; i < 8; ++i) o[i] = f2bf(fv[q2*8 + i]);
      int chunk = half*4 + q2;
      *(us8*)((char*)Bl + c*128 + ((chunk ^ (c & 7)) << 4)) = o;
    }
    if (tid < 16) {
      int cc = 128 + (tid >> 3), q = tid & 7;
      const float* s2 = ksumb + head*128 + (tid >> 3)*64 + q*8;
      us8 o;
#pragma unroll
      for (int i = 0; i < 8; ++i) o[i] = f2bf(s2[i]);
      *(us8*)((char*)Bl + cc*128 + ((q ^ (cc & 7)) << 4)) = o;
    } else if (tid < 128) {
      int idx = tid - 16;
      int cc = 130 + (idx >> 3), q = idx & 7;
      us8 o = {0,0,0,0,0,0,0,0};
      *(us8*)((char*)Bl + cc*128 + ((q ^ (cc & 7)) << 4)) = o;
    }
  }
  __syncthreads();

  f32x4 acc[2][9] = {};
  bf16x8 af[2][2];
  const size_t qrow0 = (size_t)(b * LL + l0 + w * 32);
#pragma unroll
  for (int kk = 0; kk < 2; ++kk)
#pragma unroll
    for (int m = 0; m < 2; ++m)
      af[m][kk] = *(const bf16x8*)(qkv + (qrow0 + m*16 + lr) * E3 + h*64 + kk*32 + lg*8);
#pragma unroll
  for (int kk = 0; kk < 2; ++kk)
#pragma unroll
    for (int n = 0; n < 9; ++n) {
      int cc = n*16 + lr;
      bf16x8 bb = *(const bf16x8*)((const char*)Bl + cc*128 + ((((kk*4)+lg) ^ (cc & 7)) << 4));
#pragma unroll
      for (int m = 0; m < 2; ++m)
        acc[m][n] = __builtin_amdgcn_mfma_f32_16x16x32_bf16(af[m][kk], bb, acc[m][n], 0, 0, 0);
    }

  __syncthreads();   // Bl reads done; reuse as per-wave strips
  unsigned short* strip = (unsigned short*)Bl + w * 2048;   // [32][64] bf16
#pragma unroll
  for (int m = 0; m < 2; ++m)
#pragma unroll
    for (int j = 0; j < 4; ++j) {
      int rloc = m*16 + lg*4 + j;
      int pos = l0 + w*32 + rloc;
      float s_, c_;
      __sincosf((float)pos * ANGC, &s_, &c_);
      float nc = __shfl(acc[m][8][j], lane & 48, 64);          // col 128 (lr=0)
      float ns = __shfl(acc[m][8][j], (lane & 48) | 1, 64);    // col 129 (lr=1)
      float rn = 1.0f / (c_ * nc + s_ * ns + EPSC);
#pragma unroll
      for (int n = 0; n < 4; ++n) {
        float ctx = (c_ * acc[m][n][j] + s_ * acc[m][n+4][j]) * rn;
        strip[rloc*64 + n*16 + lr] = f2bf(ctx);
      }
    }
  __syncthreads();
#pragma unroll
  for (int p = 0; p < 4; ++p) {
    int ch = p*64 + lane;
    int row = ch >> 3, piece = ch & 7;
    us8 o = *(const us8*)(strip + row*64 + piece*8);
    *(us8*)(att + (size_t)(b*LL + l0 + w*32 + row) * EE + h*64 + piece*8) = o;
  }
}

// ---------------- launcher ----------------
extern "C" void kernel_launch(void* const* d_in, const int* in_sizes, int n_in,
                              void* d_out, int out_size, void* d_ws, size_t ws_size,
                              hipStream_t stream) {
  const float* x     = (const float*)d_in[0];
  const float* W_qkv = (const float*)d_in[1];
  const float* b_qkv = (const float*)d_in[2];
  const float* W_out = (const float*)d_in[3];
  const float* b_out = (const float*)d_in[4];

  char* w = (char*)d_ws;
  unsigned short* xb  = (unsigned short*)(w);                 // 33,554,432 B
  unsigned short* qkv = (unsigned short*)(w + 33554432);      // 100,663,296 B
  unsigned short* WqT = (unsigned short*)(w + 134217728);     // 6,291,456 B
  unsigned short* WoT = (unsigned short*)(w + 140509184);     // 2,097,152 B
  float* kvb   = (float*)(w + 142606336);                     // 2,097,152 B
  float* ksum  = (float*)(w + 144703488);                     // 32,768 B  (total 144,736,256)
  unsigned short* att = xb;   // reuse: x dead after GEMM1

  hipMemsetAsync(kvb, 0, 2097152 + 32768, stream);
  k_cvt_bf16<<<8192, 256, 0, stream>>>(x, xb, 2097152);
  k_transpose_bf16<<<dim3(96, 32), 256, 0, stream>>>(W_qkv, WqT, 1024, 3072);
  k_transpose_bf16<<<dim3(32, 32), 256, 0, stream>>>(W_out, WoT, 1024, 1024);
  k_gemm<0><<<dim3(24, 128), 256, 0, stream>>>(xb, WqT, b_qkv, (void*)qkv, 3072, 1024);
  k_stage2<<<dim3(16, 64), 256, 0, stream>>>(qkv, kvb, ksum);
  k_stage3<<<dim3(32, 64), 256, 0, stream>>>(qkv, kvb, ksum, att);
  k_gemm<1><<<dim3(8, 128), 256, 0, stream>>>(att, WoT, b_out, d_out, 1024, 1024);
}

// Round 3
// 236.569 us; speedup vs baseline: 1.6172x; 1.1357x over previous
//
#include <hip/hip_runtime.h>
#include <hip/hip_bf16.h>
#include <cstdint>
#include <cstddef>

// Problem constants
#define BB 4
#define LL 4096
#define HH 16
#define M1 16384      // B*L
#define E3 3072
#define EE 1024
#define ANGC 3.8349519697141029e-4f   // (pi/2)/4096
#define EPSC 1e-4f

typedef __attribute__((ext_vector_type(8))) short bf16x8;
typedef __attribute__((ext_vector_type(4))) float f32x4;
typedef __attribute__((ext_vector_type(8))) unsigned short us8;

static __device__ __forceinline__ float bf2f(unsigned short u) {
  union { unsigned int i; float f; } a; a.i = ((unsigned int)u) << 16; return a.f;
}
static __device__ __forceinline__ unsigned short f2bf(float x) {
  union { float f; unsigned int i; } a; a.f = x;
  unsigned int r = a.i + 0x7FFFu + ((a.i >> 16) & 1u);  // RNE
  return (unsigned short)(r >> 16);
}
static __device__ __forceinline__ void gload16(const void* g, void* l) {
  __builtin_amdgcn_global_load_lds((const __attribute__((address_space(1))) void*)g,
                                   (__attribute__((address_space(3))) void*)l, 16, 0, 0);
}

#define BAR()   asm volatile("s_barrier" ::: "memory")
#define VMC4()  asm volatile("s_waitcnt vmcnt(4)" ::: "memory")
#define VMC0()  asm volatile("s_waitcnt vmcnt(0)" ::: "memory")
#define PRIO1() __builtin_amdgcn_s_setprio(1)
#define PRIO0() __builtin_amdgcn_s_setprio(0)

// ---------------- elementwise f32 -> bf16 (x) ----------------
__global__ __launch_bounds__(256) void k_cvt_bf16(const float* __restrict__ src,
                                                  unsigned short* __restrict__ dst, int n8) {
  int i = blockIdx.x * 256 + threadIdx.x;
  if (i >= n8) return;
  const float4* s = (const float4*)src + (size_t)i * 2;
  float4 a = s[0], b = s[1];
  us8 o;
  o[0]=f2bf(a.x); o[1]=f2bf(a.y); o[2]=f2bf(a.z); o[3]=f2bf(a.w);
  o[4]=f2bf(b.x); o[5]=f2bf(b.y); o[6]=f2bf(b.z); o[7]=f2bf(b.w);
  *(us8*)(dst + (size_t)i * 8) = o;
}

// ---------------- tiled transpose f32 [R][C] -> bf16 [C][R] ----------------
__global__ __launch_bounds__(256) void k_transpose_bf16(const float* __restrict__ src,
                                                        unsigned short* __restrict__ dst,
                                                        int R, int C) {
  __shared__ float tile[32][33];
  int c0 = blockIdx.x * 32, r0 = blockIdx.y * 32;
  int tx = threadIdx.x & 31, ty = threadIdx.x >> 5;
#pragma unroll
  for (int k = 0; k < 4; ++k)
    tile[ty + 8*k][tx] = src[(size_t)(r0 + ty + 8*k) * C + c0 + tx];
  __syncthreads();
#pragma unroll
  for (int k = 0; k < 4; ++k)
    dst[(size_t)(c0 + ty + 8*k) * R + r0 + tx] = f2bf(tile[tx][ty + 8*k]);
}

// ============ 256x256 8-phase bf16 MFMA GEMM (T2+T3+T4+T5, m201-style) ============
// C[M,N] = A[M,K] @ Bt[N,K]^T + bias.  MODE 0: bf16 out + relu cols<2048. MODE 1: f32 out.
// 512 thr = 8 waves (2M x 4N); per-wave 128x64 out = acc[8][4]; BK=64; LDS 128KB (2 bufs).
// LDS tile [256 rows][8 chunks of 16B], chunk-slot swizzle slot = ck ^ (row&7), applied
// BOTH sides (inverse-swizzled global source, swizzled ds_read).  Tile t parity -> buf.
// Stage schedule (per iteration computing tiles t0=2i (buf0, ph0-3), t1=2i+1 (buf1, ph4-7)):
//   ph0: t1.A0->LA1      ph1: t1.A1->LA1, (t0+2).B0->LB0   ph2: (t0+2).B1->LB0
//   ph3: --  [vmcnt(4) gate for buf1; vmcnt(0) in last iter]
//   ph4: (t0+2).A0->LA0  ph5: (t0+2).A1->LA0, (t0+3).B0->LB1  ph6: (t0+3).B1->LB1
//   ph7: --  [vmcnt(4) gate for buf0]
// Every stage target region's last ds_read drained >=1 barrier earlier (B frags are
// register-captured in ph0/ph4; A halves fully read by ph3/ph7). Race-free by barriers.

static __device__ __forceinline__ bf16x8 rdfrag(const char* base, int row, int ck) {
  return *(const bf16x8*)(base + row * 128 + (((ck) ^ ((row) & 7)) << 4));
}

static __device__ __forceinline__ void stage_half(const unsigned short* __restrict__ M, int K,
                                                  int rowbase, int half, int kt,
                                                  char* bufbase, int tid) {
  const int rr = tid >> 3, cc = tid & 7;
  char* d = bufbase + half * 16384 + tid * 16;      // linear dest: wave-uniform + lane*16
  const int r0 = half * 128 + rr, r1 = r0 + 64;     // local rows in [0,256)
  gload16(M + (size_t)(rowbase + r0) * K + kt + ((cc ^ (r0 & 7)) << 3), d);
  gload16(M + (size_t)(rowbase + r1) * K + kt + ((cc ^ (r1 & 7)) << 3), d + 8192);
}

#define PH_FIRST(AbP, BbP, AR)                                                  \
  do {                                                                          \
    _Pragma("unroll")                                                           \
    for (int n = 0; n < 4; ++n) {                                               \
      const int br = wc * 64 + n * 16 + lr;                                     \
      bF[n][0] = rdfrag((BbP), br, lg);                                         \
      bF[n][1] = rdfrag((BbP), br, 4 + lg);                                     \
    }                                                                           \
    AR[0][0] = rdfrag((AbP), wr * 128 + lr, lg);                                \
    AR[0][1] = rdfrag((AbP), wr * 128 + lr, 4 + lg);                            \
    AR[1][0] = rdfrag((AbP), wr * 128 + 16 + lr, lg);                           \
    AR[1][1] = rdfrag((AbP), wr * 128 + 16 + lr, 4 + lg);                       \
  } while (0)

#define PH_A(AbP, mb, AR)                                                       \
  do {                                                                          \
    AR[0][0] = rdfrag((AbP), wr * 128 + (mb) * 16 + lr, lg);                    \
    AR[0][1] = rdfrag((AbP), wr * 128 + (mb) * 16 + lr, 4 + lg);                \
    AR[1][0] = rdfrag((AbP), wr * 128 + (mb) * 16 + 16 + lr, lg);               \
    AR[1][1] = rdfrag((AbP), wr * 128 + (mb) * 16 + 16 + lr, 4 + lg);           \
  } while (0)

#define MMA16(mb, AR)                                                           \
  do {                                                                          \
    _Pragma("unroll")                                                           \
    for (int kk = 0; kk < 2; ++kk) {                                            \
      _Pragma("unroll")                                                         \
      for (int n = 0; n < 4; ++n) {                                             \
        acc[(mb)][n] = __builtin_amdgcn_mfma_f32_16x16x32_bf16(                 \
            AR[0][kk], bF[n][kk], acc[(mb)][n], 0, 0, 0);                       \
        acc[(mb) + 1][n] = __builtin_amdgcn_mfma_f32_16x16x32_bf16(             \
            AR[1][kk], bF[n][kk], acc[(mb) + 1][n], 0, 0, 0);                   \
      }                                                                         \
    }                                                                           \
  } while (0)

template<int MODE>
__global__ __launch_bounds__(512, 2) void k_gemm256(const unsigned short* __restrict__ A,
                                                    const unsigned short* __restrict__ Bt,
                                                    const float* __restrict__ bias,
                                                    void* __restrict__ Cout,
                                                    int N, int K) {
  __shared__ __align__(16) unsigned short lds[4][16384];  // [buf*2 + (0=A,1=B)][256 rows * 64]
  const int tid = threadIdx.x;
  const int wid = tid >> 6, lane = tid & 63;
  const int lr = lane & 15, lg = lane >> 4;
  const int wr = wid >> 2, wc = wid & 3;

  // T1 bijective XCD swizzle (nwg % 8 == 0 for both GEMMs)
  const int nx = gridDim.x;
  const int nwg = nx * gridDim.y;
  const int bid = blockIdx.y * nx + blockIdx.x;
  const int swz = (bid & 7) * (nwg >> 3) + (bid >> 3);
  const int bm = (swz / nx) * 256, bn = (swz % nx) * 256;

  char* LA0 = (char*)&lds[0][0];
  char* LB0 = (char*)&lds[1][0];
  char* LA1 = (char*)&lds[2][0];
  char* LB1 = (char*)&lds[3][0];

  f32x4 acc[8][4] = {};
  bf16x8 bF[4][2], aF[2][2], aG[2][2];

  const int NT = K >> 6, NI = NT >> 1;

  // prologue: T0 full (buf0) + T1.B (buf1); leaves exactly T1.B (4 loads) outstanding
  stage_half(A,  K, bm, 0, 0,  LA0, tid);
  stage_half(A,  K, bm, 1, 0,  LA0, tid);
  stage_half(Bt, K, bn, 0, 0,  LB0, tid);
  stage_half(Bt, K, bn, 1, 0,  LB0, tid);
  stage_half(Bt, K, bn, 0, 64, LB1, tid);
  stage_half(Bt, K, bn, 1, 64, LB1, tid);
  VMC4();
  BAR();

  for (int it = 0; it < NI; ++it) {
    const int kt1 = (2*it + 1) << 6;
    const int kt2 = (2*it + 2) << 6;
    const int kt3 = (2*it + 3) << 6;
    const bool s2 = kt2 < K, s3 = kt3 < K;

    // ---------- tile t0 : buf0 ----------
    PH_FIRST(LA0, LB0, aF);                       // 12 ds_read_b128
    stage_half(A, K, bm, 0, kt1, LA1, tid);       // t1.A0
    BAR(); PRIO1(); MMA16(0, aF); PRIO0(); BAR();

    PH_A(LA0, 2, aG);
    stage_half(A, K, bm, 1, kt1, LA1, tid);       // t1.A1  (order before t0+2.B0 matters)
    if (s2) stage_half(Bt, K, bn, 0, kt2, LB0, tid);
    BAR(); PRIO1(); MMA16(2, aG); PRIO0(); BAR();

    PH_A(LA0, 4, aF);
    if (s2) stage_half(Bt, K, bn, 1, kt2, LB0, tid);
    BAR(); PRIO1(); MMA16(4, aF); PRIO0(); BAR();

    PH_A(LA0, 6, aG);
    BAR(); PRIO1(); MMA16(6, aG); PRIO0();
    if (it == NI - 1) { VMC0(); } else { VMC4(); }   // gate buf1 (t1 fully landed)
    BAR();

    // ---------- tile t1 : buf1 ----------
    PH_FIRST(LA1, LB1, aF);
    if (s2) stage_half(A, K, bm, 0, kt2, LA0, tid);
    BAR(); PRIO1(); MMA16(0, aF); PRIO0(); BAR();

    PH_A(LA1, 2, aG);
    if (s2) stage_half(A, K, bm, 1, kt2, LA0, tid);
    if (s3) stage_half(Bt, K, bn, 0, kt3, LB1, tid);
    BAR(); PRIO1(); MMA16(2, aG); PRIO0(); BAR();

    PH_A(LA1, 4, aF);
    if (s3) stage_half(Bt, K, bn, 1, kt3, LB1, tid);
    BAR(); PRIO1(); MMA16(4, aF); PRIO0(); BAR();

    PH_A(LA1, 6, aG);
    BAR(); PRIO1(); MMA16(6, aG); PRIO0();
    VMC4();                                          // gate buf0 for next iter (t0+2 landed)
    BAR();
  }

  // ---------- epilogue: per-wave LDS strip transpose, coalesced stores ----------
  {
    float* strip = (float*)((char*)&lds[0][0] + wid * 16384);  // 16KB per wave, [16][68] f32
    float bias_v[4]; bool relu_v[4];
#pragma unroll
    for (int n = 0; n < 4; ++n) {
      int col = bn + wc*64 + n*16 + lr;
      bias_v[n] = bias[col];
      relu_v[n] = (MODE == 0) && (col < 2048);
    }
#pragma unroll
    for (int m = 0; m < 8; ++m) {
#pragma unroll
      for (int n = 0; n < 4; ++n)
#pragma unroll
        for (int j = 0; j < 4; ++j) {
          float v = acc[m][n][j] + bias_v[n];
          if (relu_v[n]) v = fmaxf(v, 0.0f);
          strip[(lg*4 + j)*68 + n*16 + lr] = v;
        }
      // wave-local RAW/WAR through LDS: compiler inserts lgkmcnt waits
#pragma unroll
      for (int itr = 0; itr < 4; ++itr) {
        int ch = itr*64 + lane;
        int row = ch >> 4, cg = ch & 15;
        float4 v = *(const float4*)(strip + row*68 + cg*4);
        size_t base = (size_t)(bm + wr*128 + m*16 + row) * N + bn + wc*64 + cg*4;
        if (MODE == 0) {
          ushort4 o;
          o.x = f2bf(v.x); o.y = f2bf(v.y); o.z = f2bf(v.z); o.w = f2bf(v.w);
          *(ushort4*)((unsigned short*)Cout + base) = o;
        } else {
          *(float4*)((float*)Cout + base) = v;
        }
      }
    }
  }
}

// ---------------- stage2: per-head KVc^T/KVs^T accumulation + k-sums ----------------
__global__ __launch_bounds__(256) void k_stage2(const unsigned short* __restrict__ qkv,
                                                float* __restrict__ kvb,
                                                float* __restrict__ ksumb) {
  __shared__ __align__(16) unsigned short kcT[4096];
  __shared__ __align__(16) unsigned short ksT[4096];
  __shared__ __align__(16) unsigned short vT [4096];
  const int tid = threadIdx.x;
  const int head = blockIdx.y;
  const int b = head >> 4, h = head & 15;
  const int lane = tid & 63, wid = tid >> 6;
  const int lr = lane & 15, lg = lane >> 4;
  const int mt = wid >> 1, eh = wid & 1;
  const int lp = tid & 31;        // l-pair: l = 2lp, 2lp+1
  const int piece = tid >> 5;     // d-range piece*8..+7

  f32x4 acc[2][4] = {};
  float ksacc = 0.0f;
  const int mtk = tid >> 6, dk = tid & 63;   // ksum role (tid<128)
  const size_t qbase = (size_t)b * LL * E3;

  for (int sc = 0; sc < 4; ++sc) {
    const int lbase = blockIdx.x * 256 + sc * 64;
    __syncthreads();
    {
      const int l0 = 2 * lp;
      const int p0 = lbase + l0;
      float s0, c0, s1, c1;
      __sincosf((float)p0 * ANGC, &s0, &c0);
      __sincosf((float)(p0 + 1) * ANGC, &s1, &c1);
      const unsigned short* kp = qkv + qbase + (size_t)p0 * E3 + 1024 + h*64 + piece*8;
      us8 kr0 = *(const us8*)kp;
      us8 kr1 = *(const us8*)(kp + E3);
      us8 vr0 = *(const us8*)(kp + 1024);
      us8 vr1 = *(const us8*)(kp + 1024 + E3);
#pragma unroll
      for (int i = 0; i < 8; ++i) {
        int d = piece*8 + i;
        float ka = bf2f(kr0[i]), kb = bf2f(kr1[i]);
        unsigned int kcp = (unsigned int)f2bf(c0*ka) | ((unsigned int)f2bf(c1*kb) << 16);
        unsigned int ksp = (unsigned int)f2bf(s0*ka) | ((unsigned int)f2bf(s1*kb) << 16);
        unsigned int vp  = (unsigned int)vr0[i] | ((unsigned int)vr1[i] << 16);
        int off = d*128 + ((((l0 >> 3) ^ (d & 7))) << 4) + (l0 & 7) * 2;
        *(unsigned int*)((char*)kcT + off) = kcp;
        *(unsigned int*)((char*)ksT + off) = ksp;
        *(unsigned int*)((char*)vT  + off) = vp;
      }
    }
    __syncthreads();
    if (tid < 128) {   // k-sums: row-sum over l of kcT/ksT row dk
      const unsigned short* basep = mtk ? ksT : kcT;
      float sum = 0.0f;
#pragma unroll
      for (int cch = 0; cch < 8; ++cch) {
        us8 r = *(const us8*)((const char*)basep + dk*128 + ((cch ^ (dk & 7)) << 4));
#pragma unroll
        for (int i = 0; i < 8; ++i) sum += bf2f(r[i]);
      }
      ksacc += sum;
    }
    {
      const unsigned short* kT = mt ? ksT : kcT;
      bf16x8 af[2][2], bf[2][4];
#pragma unroll
      for (int kk = 0; kk < 2; ++kk) {
#pragma unroll
        for (int m = 0; m < 2; ++m) {
          int e = eh*32 + m*16 + lr;
          af[kk][m] = *(const bf16x8*)((const char*)vT + e*128 + ((((kk*4)+lg) ^ (e & 7)) << 4));
        }
#pragma unroll
        for (int n = 0; n < 4; ++n) {
          int d = n*16 + lr;
          bf[kk][n] = *(const bf16x8*)((const char*)kT + d*128 + ((((kk*4)+lg) ^ (d & 7)) << 4));
        }
      }
#pragma unroll
      for (int kk = 0; kk < 2; ++kk)
#pragma unroll
        for (int m = 0; m < 2; ++m)
#pragma unroll
          for (int n = 0; n < 4; ++n)
            acc[m][n] = __builtin_amdgcn_mfma_f32_16x16x32_bf16(af[kk][m], bf[kk][n], acc[m][n], 0, 0, 0);
    }
  }
  float* dst = kvb + (size_t)head * 8192 + mt * 4096;
#pragma unroll
  for (int m = 0; m < 2; ++m)
#pragma unroll
    for (int n = 0; n < 4; ++n)
#pragma unroll
      for (int j = 0; j < 4; ++j) {
        int e = eh*32 + m*16 + lg*4 + j;
        int d = n*16 + lr;
        atomicAdd(&dst[e*64 + d], acc[m][n][j]);
      }
  if (tid < 128) atomicAdd(&ksumb[head*128 + mtk*64 + dk], ksacc);
}

// ---------------- stage3: context + norm + divide -> att bf16 [B*L][E] ----------------
__global__ __launch_bounds__(256) void k_stage3(const unsigned short* __restrict__ qkv,
                                                const float* __restrict__ kvb,
                                                const float* __restrict__ ksumb,
                                                unsigned short* __restrict__ att) {
  __shared__ __align__(16) unsigned short Bl[144 * 64];   // 18KB; reused as strips
  const int tid = threadIdx.x;
  const int head = blockIdx.y;
  const int b = head >> 4, h = head & 15;
  const int l0 = blockIdx.x * 128;
  const int lane = tid & 63, w = tid >> 6;
  const int lr = lane & 15, lg = lane >> 4;

  { // load B into LDS (bf16, XOR-swizzled chunks by (col&7))
    int c = tid >> 1, half = tid & 1;
    const float* src = kvb + (size_t)head * 8192 + (c >> 6) * 4096 + (c & 63) * 64 + half * 32;
    float fv[32];
#pragma unroll
    for (int q = 0; q < 8; ++q) *(float4*)(fv + q*4) = *(const float4*)(src + q*4);
#pragma unroll
    for (int q2 = 0; q2 < 4; ++q2) {
      us8 o;
#pragma unroll
      for (int i = 0; i < 8; ++i) o[i] = f2bf(fv[q2*8 + i]);
      int chunk = half*4 + q2;
      *(us8*)((char*)Bl + c*128 + ((chunk ^ (c & 7)) << 4)) = o;
    }
    if (tid < 16) {
      int cc = 128 + (tid >> 3), q = tid & 7;
      const float* s2 = ksumb + head*128 + (tid >> 3)*64 + q*8;
      us8 o;
#pragma unroll
      for (int i = 0; i < 8; ++i) o[i] = f2bf(s2[i]);
      *(us8*)((char*)Bl + cc*128 + ((q ^ (cc & 7)) << 4)) = o;
    } else if (tid < 128) {
      int idx = tid - 16;
      int cc = 130 + (idx >> 3), q = idx & 7;
      us8 o = {0,0,0,0,0,0,0,0};
      *(us8*)((char*)Bl + cc*128 + ((q ^ (cc & 7)) << 4)) = o;
    }
  }
  __syncthreads();

  f32x4 acc[2][9] = {};
  bf16x8 af[2][2];
  const size_t qrow0 = (size_t)(b * LL + l0 + w * 32);
#pragma unroll
  for (int kk = 0; kk < 2; ++kk)
#pragma unroll
    for (int m = 0; m < 2; ++m)
      af[m][kk] = *(const bf16x8*)(qkv + (qrow0 + m*16 + lr) * E3 + h*64 + kk*32 + lg*8);
#pragma unroll
  for (int kk = 0; kk < 2; ++kk)
#pragma unroll
    for (int n = 0; n < 9; ++n) {
      int cc = n*16 + lr;
      bf16x8 bb = *(const bf16x8*)((const char*)Bl + cc*128 + ((((kk*4)+lg) ^ (cc & 7)) << 4));
#pragma unroll
      for (int m = 0; m < 2; ++m)
        acc[m][n] = __builtin_amdgcn_mfma_f32_16x16x32_bf16(af[m][kk], bb, acc[m][n], 0, 0, 0);
    }

  __syncthreads();   // Bl reads done; reuse as per-wave strips
  unsigned short* strip = (unsigned short*)Bl + w * 2048;   // [32][64] bf16
#pragma unroll
  for (int m = 0; m < 2; ++m)
#pragma unroll
    for (int j = 0; j < 4; ++j) {
      int rloc = m*16 + lg*4 + j;
      int pos = l0 + w*32 + rloc;
      float s_, c_;
      __sincosf((float)pos * ANGC, &s_, &c_);
      float nc = __shfl(acc[m][8][j], lane & 48, 64);          // col 128 (lr=0)
      float ns = __shfl(acc[m][8][j], (lane & 48) | 1, 64);    // col 129 (lr=1)
      float rn = 1.0f / (c_ * nc + s_ * ns + EPSC);
#pragma unroll
      for (int n = 0; n < 4; ++n) {
        float ctx = (c_ * acc[m][n][j] + s_ * acc[m][n+4][j]) * rn;
        strip[rloc*64 + n*16 + lr] = f2bf(ctx);
      }
    }
  __syncthreads();
#pragma unroll
  for (int p = 0; p < 4; ++p) {
    int ch = p*64 + lane;
    int row = ch >> 3, piece = ch & 7;
    us8 o = *(const us8*)(strip + row*64 + piece*8);
    *(us8*)(att + (size_t)(b*LL + l0 + w*32 + row) * EE + h*64 + piece*8) = o;
  }
}

// ---------------- launcher ----------------
extern "C" void kernel_launch(void* const* d_in, const int* in_sizes, int n_in,
                              void* d_out, int out_size, void* d_ws, size_t ws_size,
                              hipStream_t stream) {
  const float* x     = (const float*)d_in[0];
  const float* W_qkv = (const float*)d_in[1];
  const float* b_qkv = (const float*)d_in[2];
  const float* W_out = (const float*)d_in[3];
  const float* b_out = (const float*)d_in[4];

  char* w = (char*)d_ws;
  unsigned short* xb  = (unsigned short*)(w);                 // 33,554,432 B
  unsigned short* qkv = (unsigned short*)(w + 33554432);      // 100,663,296 B
  unsigned short* WqT = (unsigned short*)(w + 134217728);     // 6,291,456 B
  unsigned short* WoT = (unsigned short*)(w + 140509184);     // 2,097,152 B
  float* kvb   = (float*)(w + 142606336);                     // 2,097,152 B
  float* ksum  = (float*)(w + 144703488);                     // 32,768 B  (total 144,736,256)
  unsigned short* att = xb;   // reuse: x dead after GEMM1

  hipMemsetAsync(kvb, 0, 2097152 + 32768, stream);
  k_cvt_bf16<<<8192, 256, 0, stream>>>(x, xb, 2097152);
  k_transpose_bf16<<<dim3(96, 32), 256, 0, stream>>>(W_qkv, WqT, 1024, 3072);
  k_transpose_bf16<<<dim3(32, 32), 256, 0, stream>>>(W_out, WoT, 1024, 1024);
  k_gemm256<0><<<dim3(12, 64), 512, 0, stream>>>(xb, WqT, b_qkv, (void*)qkv, 3072, 1024);
  k_stage2<<<dim3(16, 64), 256, 0, stream>>>(qkv, kvb, ksum);
  k_stage3<<<dim3(32, 64), 256, 0, stream>>>(qkv, kvb, ksum, att);
  k_gemm256<1><<<dim3(4, 64), 512, 0, stream>>>(att, WoT, b_out, d_out, 1024, 1024);
}

// Round 4
// 234.017 us; speedup vs baseline: 1.6348x; 1.0109x over previous
//
#include <hip/hip_runtime.h>
#include <hip/hip_bf16.h>
#include <cstdint>
#include <cstddef>

// Problem constants
#define BB 4
#define LL 4096
#define HH 16
#define M1 16384      // B*L
#define E3 3072
#define EE 1024
#define ANGC 3.8349519697141029e-4f   // (pi/2)/4096
#define EPSC 1e-4f

typedef __attribute__((ext_vector_type(8))) short bf16x8;
typedef __attribute__((ext_vector_type(4))) float f32x4;
typedef __attribute__((ext_vector_type(8))) unsigned short us8;

static __device__ __forceinline__ float bf2f(unsigned short u) {
  union { unsigned int i; float f; } a; a.i = ((unsigned int)u) << 16; return a.f;
}
static __device__ __forceinline__ unsigned short f2bf(float x) {
  union { float f; unsigned int i; } a; a.f = x;
  unsigned int r = a.i + 0x7FFFu + ((a.i >> 16) & 1u);  // RNE
  return (unsigned short)(r >> 16);
}
static __device__ __forceinline__ void gload16(const void* g, void* l) {
  __builtin_amdgcn_global_load_lds((const __attribute__((address_space(1))) void*)g,
                                   (__attribute__((address_space(3))) void*)l, 16, 0, 0);
}

#define BAR()   asm volatile("s_barrier" ::: "memory")
#define VMC4()  asm volatile("s_waitcnt vmcnt(4)" ::: "memory")
#define VMC0()  asm volatile("s_waitcnt vmcnt(0)" ::: "memory")
#define PRIO1() __builtin_amdgcn_s_setprio(1)
#define PRIO0() __builtin_amdgcn_s_setprio(0)

// ---------------- elementwise f32 -> bf16 (x) ----------------
__global__ __launch_bounds__(256) void k_cvt_bf16(const float* __restrict__ src,
                                                  unsigned short* __restrict__ dst, int n8) {
  int i = blockIdx.x * 256 + threadIdx.x;
  if (i >= n8) return;
  const float4* s = (const float4*)src + (size_t)i * 2;
  float4 a = s[0], b = s[1];
  us8 o;
  o[0]=f2bf(a.x); o[1]=f2bf(a.y); o[2]=f2bf(a.z); o[3]=f2bf(a.w);
  o[4]=f2bf(b.x); o[5]=f2bf(b.y); o[6]=f2bf(b.z); o[7]=f2bf(b.w);
  *(us8*)(dst + (size_t)i * 8) = o;
}

// ---------------- tiled transpose f32 [R][C] -> bf16 [C][R] ----------------
__global__ __launch_bounds__(256) void k_transpose_bf16(const float* __restrict__ src,
                                                        unsigned short* __restrict__ dst,
                                                        int R, int C) {
  __shared__ float tile[32][33];
  int c0 = blockIdx.x * 32, r0 = blockIdx.y * 32;
  int tx = threadIdx.x & 31, ty = threadIdx.x >> 5;
#pragma unroll
  for (int k = 0; k < 4; ++k)
    tile[ty + 8*k][tx] = src[(size_t)(r0 + ty + 8*k) * C + c0 + tx];
  __syncthreads();
#pragma unroll
  for (int k = 0; k < 4; ++k)
    dst[(size_t)(c0 + ty + 8*k) * R + r0 + tx] = f2bf(tile[tx][ty + 8*k]);
}

// ============ 256x256 8-phase bf16 MFMA GEMM (T2+T3+T4+T5, m201-style) ============
// C[M,N] = A[M,K] @ Bt[N,K]^T + bias.  MODE 0: bf16 out + relu cols<2048. MODE 1: f32 out.
// 512 thr = 8 waves (2M x 4N); per-wave 128x64 out = acc[8][4]; BK=64; LDS 128KB (2 bufs).
// LDS tile [256 rows][8 chunks of 16B], chunk-slot swizzle slot = ck ^ (row&7), applied
// BOTH sides (inverse-swizzled global source, swizzled ds_read).  Tile t parity -> buf.
// Stage schedule (per iteration computing tiles t0=2i (buf0, ph0-3), t1=2i+1 (buf1, ph4-7)):
//   ph0: t1.A0->LA1      ph1: t1.A1->LA1, (t0+2).B0->LB0   ph2: (t0+2).B1->LB0
//   ph3: --  [vmcnt(4) gate for buf1; vmcnt(0) in last iter]
//   ph4: (t0+2).A0->LA0  ph5: (t0+2).A1->LA0, (t0+3).B0->LB1  ph6: (t0+3).B1->LB1
//   ph7: --  [vmcnt(4) gate for buf0]
// Every stage target region's last ds_read drained >=1 barrier earlier (B frags are
// register-captured in ph0/ph4; A halves fully read by ph3/ph7). Race-free by barriers.

static __device__ __forceinline__ bf16x8 rdfrag(const char* base, int row, int ck) {
  return *(const bf16x8*)(base + row * 128 + (((ck) ^ ((row) & 7)) << 4));
}

static __device__ __forceinline__ void stage_half(const unsigned short* __restrict__ M, int K,
                                                  int rowbase, int half, int kt,
                                                  char* bufbase, int tid) {
  const int rr = tid >> 3, cc = tid & 7;
  char* d = bufbase + half * 16384 + tid * 16;      // linear dest: wave-uniform + lane*16
  const int r0 = half * 128 + rr, r1 = r0 + 64;     // local rows in [0,256)
  gload16(M + (size_t)(rowbase + r0) * K + kt + ((cc ^ (r0 & 7)) << 3), d);
  gload16(M + (size_t)(rowbase + r1) * K + kt + ((cc ^ (r1 & 7)) << 3), d + 8192);
}

#define PH_FIRST(AbP, BbP, AR)                                                  \
  do {                                                                          \
    _Pragma("unroll")                                                           \
    for (int n = 0; n < 4; ++n) {                                               \
      const int br = wc * 64 + n * 16 + lr;                                     \
      bF[n][0] = rdfrag((BbP), br, lg);                                         \
      bF[n][1] = rdfrag((BbP), br, 4 + lg);                                     \
    }                                                                           \
    AR[0][0] = rdfrag((AbP), wr * 128 + lr, lg);                                \
    AR[0][1] = rdfrag((AbP), wr * 128 + lr, 4 + lg);                            \
    AR[1][0] = rdfrag((AbP), wr * 128 + 16 + lr, lg);                           \
    AR[1][1] = rdfrag((AbP), wr * 128 + 16 + lr, 4 + lg);                       \
  } while (0)

#define PH_A(AbP, mb, AR)                                                       \
  do {                                                                          \
    AR[0][0] = rdfrag((AbP), wr * 128 + (mb) * 16 + lr, lg);                    \
    AR[0][1] = rdfrag((AbP), wr * 128 + (mb) * 16 + lr, 4 + lg);                \
    AR[1][0] = rdfrag((AbP), wr * 128 + (mb) * 16 + 16 + lr, lg);               \
    AR[1][1] = rdfrag((AbP), wr * 128 + (mb) * 16 + 16 + lr, 4 + lg);           \
  } while (0)

#define MMA16(mb, AR)                                                           \
  do {                                                                          \
    _Pragma("unroll")                                                           \
    for (int kk = 0; kk < 2; ++kk) {                                            \
      _Pragma("unroll")                                                         \
      for (int n = 0; n < 4; ++n) {                                             \
        acc[(mb)][n] = __builtin_amdgcn_mfma_f32_16x16x32_bf16(                 \
            AR[0][kk], bF[n][kk], acc[(mb)][n], 0, 0, 0);                       \
        acc[(mb) + 1][n] = __builtin_amdgcn_mfma_f32_16x16x32_bf16(             \
            AR[1][kk], bF[n][kk], acc[(mb) + 1][n], 0, 0, 0);                   \
      }                                                                         \
    }                                                                           \
  } while (0)

template<int MODE>
__global__ __launch_bounds__(512, 2) void k_gemm256(const unsigned short* __restrict__ A,
                                                    const unsigned short* __restrict__ Bt,
                                                    const float* __restrict__ bias,
                                                    void* __restrict__ Cout,
                                                    int N, int K) {
  __shared__ __align__(16) unsigned short lds[4][16384];  // [buf*2 + (0=A,1=B)][256 rows * 64]
  const int tid = threadIdx.x;
  const int wid = tid >> 6, lane = tid & 63;
  const int lr = lane & 15, lg = lane >> 4;
  const int wr = wid >> 2, wc = wid & 3;

  // L2-locality mapping: per-XCD rectangles of 8(by) x 4(bx) tiles.
  // Dispatch index d lands on XCD ~ d&7 (round-robin); give each XCD a disjoint
  // 8-row by-band and walk bx in groups of 4: concurrent working set per XCD =
  // 8 A-panels (4MB) + 4 B-panels (2MB), each A panel shared by 4 concurrent
  // blocks, each B panel by 8 -> L2-resident staging instead of L3.
  // Requires gridDim.y == 64 (M=16384) and gridDim.x % 4 == 0 (12 / 4). Bijective.
  const int nx = gridDim.x;
  const int rawbid = blockIdx.y * nx + blockIdx.x;
  const int xcd = rawbid & 7, s = rawbid >> 3;
  const int g = s >> 5, r = s & 31;
  const int bm = (xcd * 8 + (r & 7)) * 256;
  const int bn = (g * 4 + (r >> 3)) * 256;

  char* LA0 = (char*)&lds[0][0];
  char* LB0 = (char*)&lds[1][0];
  char* LA1 = (char*)&lds[2][0];
  char* LB1 = (char*)&lds[3][0];

  f32x4 acc[8][4] = {};
  bf16x8 bF[4][2], aF[2][2], aG[2][2];

  const int NT = K >> 6, NI = NT >> 1;

  // prologue: T0 full (buf0) + T1.B (buf1); leaves exactly T1.B (4 loads) outstanding
  stage_half(A,  K, bm, 0, 0,  LA0, tid);
  stage_half(A,  K, bm, 1, 0,  LA0, tid);
  stage_half(Bt, K, bn, 0, 0,  LB0, tid);
  stage_half(Bt, K, bn, 1, 0,  LB0, tid);
  stage_half(Bt, K, bn, 0, 64, LB1, tid);
  stage_half(Bt, K, bn, 1, 64, LB1, tid);
  VMC4();
  BAR();

  for (int it = 0; it < NI; ++it) {
    const int kt1 = (2*it + 1) << 6;
    const int kt2 = (2*it + 2) << 6;
    const int kt3 = (2*it + 3) << 6;
    const bool s2 = kt2 < K, s3 = kt3 < K;

    // ---------- tile t0 : buf0 ----------
    PH_FIRST(LA0, LB0, aF);                       // 12 ds_read_b128
    stage_half(A, K, bm, 0, kt1, LA1, tid);       // t1.A0
    BAR(); PRIO1(); MMA16(0, aF); PRIO0(); BAR();

    PH_A(LA0, 2, aG);
    stage_half(A, K, bm, 1, kt1, LA1, tid);       // t1.A1  (order before t0+2.B0 matters)
    if (s2) stage_half(Bt, K, bn, 0, kt2, LB0, tid);
    BAR(); PRIO1(); MMA16(2, aG); PRIO0(); BAR();

    PH_A(LA0, 4, aF);
    if (s2) stage_half(Bt, K, bn, 1, kt2, LB0, tid);
    BAR(); PRIO1(); MMA16(4, aF); PRIO0(); BAR();

    PH_A(LA0, 6, aG);
    BAR(); PRIO1(); MMA16(6, aG); PRIO0();
    if (it == NI - 1) { VMC0(); } else { VMC4(); }   // gate buf1 (t1 fully landed)
    BAR();

    // ---------- tile t1 : buf1 ----------
    PH_FIRST(LA1, LB1, aF);
    if (s2) stage_half(A, K, bm, 0, kt2, LA0, tid);
    BAR(); PRIO1(); MMA16(0, aF); PRIO0(); BAR();

    PH_A(LA1, 2, aG);
    if (s2) stage_half(A, K, bm, 1, kt2, LA0, tid);
    if (s3) stage_half(Bt, K, bn, 0, kt3, LB1, tid);
    BAR(); PRIO1(); MMA16(2, aG); PRIO0(); BAR();

    PH_A(LA1, 4, aF);
    if (s3) stage_half(Bt, K, bn, 1, kt3, LB1, tid);
    BAR(); PRIO1(); MMA16(4, aF); PRIO0(); BAR();

    PH_A(LA1, 6, aG);
    BAR(); PRIO1(); MMA16(6, aG); PRIO0();
    VMC4();                                          // gate buf0 for next iter (t0+2 landed)
    BAR();
  }

  // ---------- epilogue: per-wave LDS strip transpose, coalesced stores ----------
  {
    float* strip = (float*)((char*)&lds[0][0] + wid * 16384);  // 16KB per wave, [16][68] f32
    float bias_v[4]; bool relu_v[4];
#pragma unroll
    for (int n = 0; n < 4; ++n) {
      int col = bn + wc*64 + n*16 + lr;
      bias_v[n] = bias[col];
      relu_v[n] = (MODE == 0) && (col < 2048);
    }
#pragma unroll
    for (int m = 0; m < 8; ++m) {
#pragma unroll
      for (int n = 0; n < 4; ++n)
#pragma unroll
        for (int j = 0; j < 4; ++j) {
          float v = acc[m][n][j] + bias_v[n];
          if (relu_v[n]) v = fmaxf(v, 0.0f);
          strip[(lg*4 + j)*68 + n*16 + lr] = v;
        }
      // wave-local RAW/WAR through LDS: compiler inserts lgkmcnt waits
#pragma unroll
      for (int itr = 0; itr < 4; ++itr) {
        int ch = itr*64 + lane;
        int row = ch >> 4, cg = ch & 15;
        float4 v = *(const float4*)(strip + row*68 + cg*4);
        size_t base = (size_t)(bm + wr*128 + m*16 + row) * N + bn + wc*64 + cg*4;
        if (MODE == 0) {
          ushort4 o;
          o.x = f2bf(v.x); o.y = f2bf(v.y); o.z = f2bf(v.z); o.w = f2bf(v.w);
          *(ushort4*)((unsigned short*)Cout + base) = o;
        } else {
          *(float4*)((float*)Cout + base) = v;
        }
      }
    }
  }
}

// ---------------- stage2: per-head KVc^T/KVs^T accumulation + k-sums ----------------
__global__ __launch_bounds__(256) void k_stage2(const unsigned short* __restrict__ qkv,
                                                float* __restrict__ kvb,
                                                float* __restrict__ ksumb) {
  __shared__ __align__(16) unsigned short kcT[4096];
  __shared__ __align__(16) unsigned short ksT[4096];
  __shared__ __align__(16) unsigned short vT [4096];
  const int tid = threadIdx.x;
  const int head = blockIdx.y;
  const int b = head >> 4, h = head & 15;
  const int lane = tid & 63, wid = tid >> 6;
  const int lr = lane & 15, lg = lane >> 4;
  const int mt = wid >> 1, eh = wid & 1;
  const int lp = tid & 31;        // l-pair: l = 2lp, 2lp+1
  const int piece = tid >> 5;     // d-range piece*8..+7

  f32x4 acc[2][4] = {};
  float ksacc = 0.0f;
  const int mtk = tid >> 6, dk = tid & 63;   // ksum role (tid<128)
  const size_t qbase = (size_t)b * LL * E3;

  for (int sc = 0; sc < 4; ++sc) {
    const int lbase = blockIdx.x * 256 + sc * 64;
    __syncthreads();
    {
      const int l0 = 2 * lp;
      const int p0 = lbase + l0;
      float s0, c0, s1, c1;
      __sincosf((float)p0 * ANGC, &s0, &c0);
      __sincosf((float)(p0 + 1) * ANGC, &s1, &c1);
      const unsigned short* kp = qkv + qbase + (size_t)p0 * E3 + 1024 + h*64 + piece*8;
      us8 kr0 = *(const us8*)kp;
      us8 kr1 = *(const us8*)(kp + E3);
      us8 vr0 = *(const us8*)(kp + 1024);
      us8 vr1 = *(const us8*)(kp + 1024 + E3);
#pragma unroll
      for (int i = 0; i < 8; ++i) {
        int d = piece*8 + i;
        float ka = bf2f(kr0[i]), kb = bf2f(kr1[i]);
        unsigned int kcp = (unsigned int)f2bf(c0*ka) | ((unsigned int)f2bf(c1*kb) << 16);
        unsigned int ksp = (unsigned int)f2bf(s0*ka) | ((unsigned int)f2bf(s1*kb) << 16);
        unsigned int vp  = (unsigned int)vr0[i] | ((unsigned int)vr1[i] << 16);
        int off = d*128 + ((((l0 >> 3) ^ (d & 7))) << 4) + (l0 & 7) * 2;
        *(unsigned int*)((char*)kcT + off) = kcp;
        *(unsigned int*)((char*)ksT + off) = ksp;
        *(unsigned int*)((char*)vT  + off) = vp;
      }
    }
    __syncthreads();
    if (tid < 128) {   // k-sums: row-sum over l of kcT/ksT row dk
      const unsigned short* basep = mtk ? ksT : kcT;
      float sum = 0.0f;
#pragma unroll
      for (int cch = 0; cch < 8; ++cch) {
        us8 r = *(const us8*)((const char*)basep + dk*128 + ((cch ^ (dk & 7)) << 4));
#pragma unroll
        for (int i = 0; i < 8; ++i) sum += bf2f(r[i]);
      }
      ksacc += sum;
    }
    {
      const unsigned short* kT = mt ? ksT : kcT;
      bf16x8 af[2][2], bf[2][4];
#pragma unroll
      for (int kk = 0; kk < 2; ++kk) {
#pragma unroll
        for (int m = 0; m < 2; ++m) {
          int e = eh*32 + m*16 + lr;
          af[kk][m] = *(const bf16x8*)((const char*)vT + e*128 + ((((kk*4)+lg) ^ (e & 7)) << 4));
        }
#pragma unroll
        for (int n = 0; n < 4; ++n) {
          int d = n*16 + lr;
          bf[kk][n] = *(const bf16x8*)((const char*)kT + d*128 + ((((kk*4)+lg) ^ (d & 7)) << 4));
        }
      }
#pragma unroll
      for (int kk = 0; kk < 2; ++kk)
#pragma unroll
        for (int m = 0; m < 2; ++m)
#pragma unroll
          for (int n = 0; n < 4; ++n)
            acc[m][n] = __builtin_amdgcn_mfma_f32_16x16x32_bf16(af[kk][m], bf[kk][n], acc[m][n], 0, 0, 0);
    }
  }
  float* dst = kvb + (size_t)head * 8192 + mt * 4096;
#pragma unroll
  for (int m = 0; m < 2; ++m)
#pragma unroll
    for (int n = 0; n < 4; ++n)
#pragma unroll
      for (int j = 0; j < 4; ++j) {
        int e = eh*32 + m*16 + lg*4 + j;
        int d = n*16 + lr;
        atomicAdd(&dst[e*64 + d], acc[m][n][j]);
      }
  if (tid < 128) atomicAdd(&ksumb[head*128 + mtk*64 + dk], ksacc);
}

// ---------------- stage3: context + norm + divide -> att bf16 [B*L][E] ----------------
__global__ __launch_bounds__(256) void k_stage3(const unsigned short* __restrict__ qkv,
                                                const float* __restrict__ kvb,
                                                const float* __restrict__ ksumb,
                                                unsigned short* __restrict__ att) {
  __shared__ __align__(16) unsigned short Bl[144 * 64];   // 18KB; reused as strips
  const int tid = threadIdx.x;
  const int head = blockIdx.y;
  const int b = head >> 4, h = head & 15;
  const int l0 = blockIdx.x * 128;
  const int lane = tid & 63, w = tid >> 6;
  const int lr = lane & 15, lg = lane >> 4;

  { // load B into LDS (bf16, XOR-swizzled chunks by (col&7))
    int c = tid >> 1, half = tid & 1;
    const float* src = kvb + (size_t)head * 8192 + (c >> 6) * 4096 + (c & 63) * 64 + half * 32;
    float fv[32];
#pragma unroll
    for (int q = 0; q < 8; ++q) *(float4*)(fv + q*4) = *(const float4*)(src + q*4);
#pragma unroll
    for (int q2 = 0; q2 < 4; ++q2) {
      us8 o;
#pragma unroll
      for (int i = 0; i < 8; ++i) o[i] = f2bf(fv[q2*8 + i]);
      int chunk = half*4 + q2;
      *(us8*)((char*)Bl + c*128 + ((chunk ^ (c & 7)) << 4)) = o;
    }
    if (tid < 16) {
      int cc = 128 + (tid >> 3), q = tid & 7;
      const float* s2 = ksumb + head*128 + (tid >> 3)*64 + q*8;
      us8 o;
#pragma unroll
      for (int i = 0; i < 8; ++i) o[i] = f2bf(s2[i]);
      *(us8*)((char*)Bl + cc*128 + ((q ^ (cc & 7)) << 4)) = o;
    } else if (tid < 128) {
      int idx = tid - 16;
      int cc = 130 + (idx >> 3), q = idx & 7;
      us8 o = {0,0,0,0,0,0,0,0};
      *(us8*)((char*)Bl + cc*128 + ((q ^ (cc & 7)) << 4)) = o;
    }
  }
  __syncthreads();

  f32x4 acc[2][9] = {};
  bf16x8 af[2][2];
  const size_t qrow0 = (size_t)(b * LL + l0 + w * 32);
#pragma unroll
  for (int kk = 0; kk < 2; ++kk)
#pragma unroll
    for (int m = 0; m < 2; ++m)
      af[m][kk] = *(const bf16x8*)(qkv + (qrow0 + m*16 + lr) * E3 + h*64 + kk*32 + lg*8);
#pragma unroll
  for (int kk = 0; kk < 2; ++kk)
#pragma unroll
    for (int n = 0; n < 9; ++n) {
      int cc = n*16 + lr;
      bf16x8 bb = *(const bf16x8*)((const char*)Bl + cc*128 + ((((kk*4)+lg) ^ (cc & 7)) << 4));
#pragma unroll
      for (int m = 0; m < 2; ++m)
        acc[m][n] = __builtin_amdgcn_mfma_f32_16x16x32_bf16(af[m][kk], bb, acc[m][n], 0, 0, 0);
    }

  __syncthreads();   // Bl reads done; reuse as per-wave strips
  unsigned short* strip = (unsigned short*)Bl + w * 2048;   // [32][64] bf16
#pragma unroll
  for (int m = 0; m < 2; ++m)
#pragma unroll
    for (int j = 0; j < 4; ++j) {
      int rloc = m*16 + lg*4 + j;
      int pos = l0 + w*32 + rloc;
      float s_, c_;
      __sincosf((float)pos * ANGC, &s_, &c_);
      float nc = __shfl(acc[m][8][j], lane & 48, 64);          // col 128 (lr=0)
      float ns = __shfl(acc[m][8][j], (lane & 48) | 1, 64);    // col 129 (lr=1)
      float rn = 1.0f / (c_ * nc + s_ * ns + EPSC);
#pragma unroll
      for (int n = 0; n < 4; ++n) {
        float ctx = (c_ * acc[m][n][j] + s_ * acc[m][n+4][j]) * rn;
        strip[rloc*64 + n*16 + lr] = f2bf(ctx);
      }
    }
  __syncthreads();
#pragma unroll
  for (int p = 0; p < 4; ++p) {
    int ch = p*64 + lane;
    int row = ch >> 3, piece = ch & 7;
    us8 o = *(const us8*)(strip + row*64 + piece*8);
    *(us8*)(att + (size_t)(b*LL + l0 + w*32 + row) * EE + h*64 + piece*8) = o;
  }
}

// ---------------- launcher ----------------
extern "C" void kernel_launch(void* const* d_in, const int* in_sizes, int n_in,
                              void* d_out, int out_size, void* d_ws, size_t ws_size,
                              hipStream_t stream) {
  const float* x     = (const float*)d_in[0];
  const float* W_qkv = (const float*)d_in[1];
  const float* b_qkv = (const float*)d_in[2];
  const float* W_out = (const float*)d_in[3];
  const float* b_out = (const float*)d_in[4];

  char* w = (char*)d_ws;
  unsigned short* xb  = (unsigned short*)(w);                 // 33,554,432 B
  unsigned short* qkv = (unsigned short*)(w + 33554432);      // 100,663,296 B
  unsigned short* WqT = (unsigned short*)(w + 134217728);     // 6,291,456 B
  unsigned short* WoT = (unsigned short*)(w + 140509184);     // 2,097,152 B
  float* kvb   = (float*)(w + 142606336);                     // 2,097,152 B
  float* ksum  = (float*)(w + 144703488);                     // 32,768 B  (total 144,736,256)
  unsigned short* att = xb;   // reuse: x dead after GEMM1

  hipMemsetAsync(kvb, 0, 2097152 + 32768, stream);
  k_cvt_bf16<<<8192, 256, 0, stream>>>(x, xb, 2097152);
  k_transpose_bf16<<<dim3(96, 32), 256, 0, stream>>>(W_qkv, WqT, 1024, 3072);
  k_transpose_bf16<<<dim3(32, 32), 256, 0, stream>>>(W_out, WoT, 1024, 1024);
  k_gemm256<0><<<dim3(12, 64), 512, 0, stream>>>(xb, WqT, b_qkv, (void*)qkv, 3072, 1024);
  k_stage2<<<dim3(16, 64), 256, 0, stream>>>(qkv, kvb, ksum);
  k_stage3<<<dim3(32, 64), 256, 0, stream>>>(qkv, kvb, ksum, att);
  k_gemm256<1><<<dim3(4, 64), 512, 0, stream>>>(att, WoT, b_out, d_out, 1024, 1024);
}